// Round 1
// baseline (304.682 us; speedup 1.0000x reference)
//
#include <hip/hip_runtime.h>
#include <math.h>

#define B_    8
#define S_    128
#define K_    12
#define DAR_  256
#define DENC_ 256
#define NNEG_ 128
#define W_    116          // S - K
#define BW_   (B_ * W_)    // 928

// ---------------------------------------------------------------------------
// zero the 24 output accumulators (d_out is poisoned 0xAA before every launch)
// ---------------------------------------------------------------------------
__global__ void zero_out_kernel(float* out) {
    if (threadIdx.x < 24) out[threadIdx.x] = 0.0f;
}

// ---------------------------------------------------------------------------
// Stage 1: locC[k][bw][e] = sum_d c[bw][d] * Wp[k][e][d]
//   c[bw][d]    = cFeature[b*S + w][d],  bw = b*W + w, w < W
//   64x64 tile per block, 4x4 micro-tile per thread, LDS staged (d-major).
// ---------------------------------------------------------------------------
__global__ __launch_bounds__(256) void stage1_gemm(
    const float* __restrict__ cFeat,   // (B, S, DAR)
    const float* __restrict__ Wp,      // (K, DENC, DAR)
    float* __restrict__ locC)          // (K, BW, DENC)
{
    __shared__ float As[16 * 64];      // As[d_local][row]
    __shared__ float Bs[16 * 64];      // Bs[d_local][e_row]

    const int tid = threadIdx.x;
    const int mt = blockIdx.x;         // bw tile (15 tiles of 64, last partial)
    const int nt = blockIdx.y;         // e tile (4 tiles of 64)
    const int k  = blockIdx.z;         // 12

    const int tx = tid & 15;           // 16 col-groups (e)
    const int ty = tid >> 4;           // 16 row-groups (bw)

    // staging indices: each thread loads one float4 per tile
    const int lr = tid >> 2;           // row 0..63 within tile
    const int dg = tid & 3;            // d-group 0..3 (4 floats each)

    const int bw_l = mt * 64 + lr;
    const bool aval = (bw_l < BW_);
    const int bwc = aval ? bw_l : 0;           // clamp to avoid OOB pointer
    const int b = bwc / W_;
    const int w = bwc - b * W_;
    const float* arow = cFeat + (size_t)(b * S_ + w) * DAR_;

    const int erow = nt * 64 + lr;             // always < 256
    const float* brow = Wp + (size_t)(k * DENC_ + erow) * DAR_;

    float acc[4][4];
#pragma unroll
    for (int i = 0; i < 4; ++i)
#pragma unroll
        for (int j = 0; j < 4; ++j) acc[i][j] = 0.0f;

    for (int d0 = 0; d0 < DAR_; d0 += 16) {
        float4 av = aval ? *(const float4*)(arow + d0 + dg * 4)
                         : make_float4(0.f, 0.f, 0.f, 0.f);
        float4 bv = *(const float4*)(brow + d0 + dg * 4);

        __syncthreads();
        As[(dg * 4 + 0) * 64 + lr] = av.x;
        As[(dg * 4 + 1) * 64 + lr] = av.y;
        As[(dg * 4 + 2) * 64 + lr] = av.z;
        As[(dg * 4 + 3) * 64 + lr] = av.w;
        Bs[(dg * 4 + 0) * 64 + lr] = bv.x;
        Bs[(dg * 4 + 1) * 64 + lr] = bv.y;
        Bs[(dg * 4 + 2) * 64 + lr] = bv.z;
        Bs[(dg * 4 + 3) * 64 + lr] = bv.w;
        __syncthreads();

#pragma unroll
        for (int d = 0; d < 16; ++d) {
            float4 aa = *(const float4*)&As[d * 64 + ty * 4];
            float4 bb = *(const float4*)&Bs[d * 64 + tx * 4];
            float ar[4] = {aa.x, aa.y, aa.z, aa.w};
            float br[4] = {bb.x, bb.y, bb.z, bb.w};
#pragma unroll
            for (int i = 0; i < 4; ++i)
#pragma unroll
                for (int j = 0; j < 4; ++j)
                    acc[i][j] = fmaf(ar[i], br[j], acc[i][j]);
        }
    }

    const int e0 = nt * 64 + tx * 4;
#pragma unroll
    for (int i = 0; i < 4; ++i) {
        const int bwo = mt * 64 + ty * 4 + i;
        if (bwo < BW_) {
            float4 v = make_float4(acc[i][0], acc[i][1], acc[i][2], acc[i][3]);
            *(float4*)(locC + ((size_t)k * BW_ + bwo) * DENC_ + e0) = v;
        }
    }
}

// ---------------------------------------------------------------------------
// Stage 2: one block per (b,w). Scores, LSE, loss/acc accumulation.
//   scores[k][0]   = dot(locC[k,bw], enc[b, w+k+1]) / 256
//   scores[k][1+n] = dot(locC[k,bw], enc[batchIdx[i], (seqIdx[i]+w)%S]) / 256
//     with i = (b*NNEG + n)*W + w
// ---------------------------------------------------------------------------
__global__ __launch_bounds__(256) void stage2_score(
    const float* __restrict__ enc,      // (B, S, DENC)
    const float* __restrict__ locC,     // (K, BW, DENC)
    const int* __restrict__ batchIdx,
    const int* __restrict__ seqIdx,
    float* __restrict__ out)            // 24 floats: 12 losses then 12 accs
{
    __shared__ float lc[K_ * DENC_];        // 12 KB
    __shared__ float buf[4 * K_ * NNEG_];   // 24 KB  (per-wave partials)
    __shared__ float sc[K_ * 132];          // 6.2 KB (129 logits per k, padded)
    __shared__ float posbuf[K_ * 16];       // 768 B

    const int tid = threadIdx.x;
    const int bw = blockIdx.x;              // 0..927
    const int b = bw / W_;
    const int w = bw - b * W_;

    // ---- load the 12 locC rows for this (b,w) into LDS ----
#pragma unroll
    for (int i = 0; i < 3; ++i) {
        const int q4 = tid + 256 * i;       // 0..767 float4 index
        const int k  = q4 >> 6;
        const int e4 = q4 & 63;
        float4 v = *(const float4*)(locC + ((size_t)k * BW_ + bw) * DENC_ + e4 * 4);
        *(float4*)&lc[k * DENC_ + e4 * 4] = v;
    }
    __syncthreads();

    // ---- positive-score partials (192 threads: 12 k x 16 segments) ----
    if (tid < 192) {
        const int k = tid >> 4, seg = tid & 15;
        const float* prow = enc + (size_t)(b * S_ + w + k + 1) * DENC_ + seg * 16;
        const float* lrow = lc + k * DENC_ + seg * 16;
        float s = 0.f;
#pragma unroll
        for (int g = 0; g < 4; ++g) {
            float4 pv = *(const float4*)(prow + g * 4);
            float4 lv = *(const float4*)(lrow + g * 4);
            s += pv.x * lv.x + pv.y * lv.y + pv.z * lv.z + pv.w * lv.w;
        }
        posbuf[tid] = s;
    }

    // ---- negative-score partials ----
    // thread -> e-slice h (8 slices of 32 e), n-base nb (32), 4 n's per thread
    const int h  = tid >> 5;   // 0..7
    const int nb = tid & 31;   // 0..31

    const float* rowp[4];
#pragma unroll
    for (int j = 0; j < 4; ++j) {
        const int n = nb + 32 * j;
        const int i_idx = (b * NNEG_ + n) * W_ + w;
        const int bi = batchIdx[i_idx];
        int si = seqIdx[i_idx] + w;          // seqIdx in [1,S), w <= 115 -> < 243
        if (si >= S_) si -= S_;
        rowp[j] = enc + (size_t)(bi * S_ + si) * DENC_ + h * 32;
    }

    float acc[K_][4];
#pragma unroll
    for (int k = 0; k < K_; ++k)
#pragma unroll
        for (int j = 0; j < 4; ++j) acc[k][j] = 0.f;

    for (int g = 0; g < 8; ++g) {
        float4 v[4];
#pragma unroll
        for (int j = 0; j < 4; ++j) v[j] = *(const float4*)(rowp[j] + g * 4);
#pragma unroll
        for (int k = 0; k < K_; ++k) {
            float4 l = *(const float4*)&lc[k * DENC_ + h * 32 + g * 4];
#pragma unroll
            for (int j = 0; j < 4; ++j) {
                acc[k][j] = fmaf(l.x, v[j].x,
                            fmaf(l.y, v[j].y,
                            fmaf(l.z, v[j].z,
                            fmaf(l.w, v[j].w, acc[k][j]))));
            }
        }
    }

    // combine the two e-slices that live in the same wave (lane ^ 32)
    const int lane = tid & 63;
    const int wave = tid >> 6;
#pragma unroll
    for (int k = 0; k < K_; ++k)
#pragma unroll
        for (int j = 0; j < 4; ++j)
            acc[k][j] += __shfl_xor(acc[k][j], 32, 64);

    if (lane < 32) {
#pragma unroll
        for (int k = 0; k < K_; ++k)
#pragma unroll
            for (int j = 0; j < 4; ++j)
                buf[(wave * K_ + k) * NNEG_ + nb + 32 * j] = acc[k][j];
    }
    __syncthreads();

    // ---- final reduction into the logit table sc[k][0..128] ----
    const float inv_denc = 1.0f / (float)DENC_;
#pragma unroll
    for (int i = 0; i < 6; ++i) {
        const int p = tid + 256 * i;        // 0..1535
        const int k = p >> 7;
        const int n = p & 127;
        float s = buf[(0 * K_ + k) * NNEG_ + n]
                + buf[(1 * K_ + k) * NNEG_ + n]
                + buf[(2 * K_ + k) * NNEG_ + n]
                + buf[(3 * K_ + k) * NNEG_ + n];
        sc[k * 132 + 1 + n] = s * inv_denc;
    }
    if (tid < K_) {
        float s = 0.f;
#pragma unroll
        for (int seg = 0; seg < 16; ++seg) s += posbuf[tid * 16 + seg];
        sc[tid * 132] = s * inv_denc;
    }
    __syncthreads();

    // ---- LSE + argmax per k (wave wv handles k = wv, wv+4, wv+8) ----
    const float invBW = 1.0f / (float)BW_;
    for (int k = wave; k < K_; k += 4) {
        const float sc0 = sc[k * 132];              // logit j=0 (pos)
        const float a  = sc[k * 132 + lane];        // j = lane   (0..63)
        const float b2 = sc[k * 132 + 64 + lane];   // j = 64+lane (64..127)
        const float cc = (lane == 0) ? sc[k * 132 + 128] : -INFINITY;  // j=128
        const float an = (lane == 0) ? -INFINITY : a;  // exclude j=0 from neg-max

        float mn = fmaxf(fmaxf(an, b2), cc);
#pragma unroll
        for (int off = 1; off < 64; off <<= 1)
            mn = fmaxf(mn, __shfl_xor(mn, off, 64));
        // mn = max over negatives (j>=1), broadcast to all lanes

        const float m = fmaxf(mn, sc0);             // global max for stability
        float s = expf(a - m) + expf(b2 - m) + expf(cc - m);
#pragma unroll
        for (int off = 1; off < 64; off <<= 1)
            s += __shfl_xor(s, off, 64);

        if (lane == 0) {
            const float lse = m + logf(s);
            atomicAdd(out + k,       (lse - sc0) * invBW);
            atomicAdd(out + K_ + k,  (sc0 >= mn) ? invBW : 0.0f);
        }
    }
}

// ---------------------------------------------------------------------------
extern "C" void kernel_launch(void* const* d_in, const int* in_sizes, int n_in,
                              void* d_out, int out_size, void* d_ws, size_t ws_size,
                              hipStream_t stream) {
    const float* cFeat    = (const float*)d_in[0];
    const float* enc      = (const float*)d_in[1];
    const float* Wp       = (const float*)d_in[2];
    const int*   batchIdx = (const int*)d_in[3];
    const int*   seqIdx   = (const int*)d_in[4];
    float* out  = (float*)d_out;
    float* locC = (float*)d_ws;     // (K, BW, DENC) fp32 = 11.4 MB

    hipLaunchKernelGGL(zero_out_kernel, dim3(1), dim3(32), 0, stream, out);
    hipLaunchKernelGGL(stage1_gemm, dim3(15, 4, 12), dim3(256), 0, stream,
                       cFeat, Wp, locC);
    hipLaunchKernelGGL(stage2_score, dim3(BW_), dim3(256), 0, stream,
                       enc, locC, batchIdx, seqIdx, out);
}

// Round 2
// 133.560 us; speedup vs baseline: 2.2812x; 2.2812x over previous
//
#include <hip/hip_runtime.h>
#include <math.h>

#define B_    8
#define S_    128
#define K_    12
#define DAR_  256
#define DENC_ 256
#define NNEG_ 128
#define W_    116          // S - K
#define BW_   (B_ * W_)    // 928

// ---------------------------------------------------------------------------
// Stage 1: locC[k][bw][e] = sum_d c[bw][d] * Wp[k][e][d]
//   64x64 tile per block, 4x4 micro-tile per thread, LDS staged (d-major).
// ---------------------------------------------------------------------------
__global__ __launch_bounds__(256) void stage1_gemm(
    const float* __restrict__ cFeat,   // (B, S, DAR)
    const float* __restrict__ Wp,      // (K, DENC, DAR)
    float* __restrict__ locC)          // (K, BW, DENC)
{
    __shared__ float As[16 * 64];      // As[d_local][row]
    __shared__ float Bs[16 * 64];      // Bs[d_local][e_row]

    const int tid = threadIdx.x;
    const int mt = blockIdx.x;         // bw tile (15 tiles of 64, last partial)
    const int nt = blockIdx.y;         // e tile (4 tiles of 64)
    const int k  = blockIdx.z;         // 12

    const int tx = tid & 15;           // 16 col-groups (e)
    const int ty = tid >> 4;           // 16 row-groups (bw)

    const int lr = tid >> 2;           // row 0..63 within tile
    const int dg = tid & 3;            // d-group 0..3 (4 floats each)

    const int bw_l = mt * 64 + lr;
    const bool aval = (bw_l < BW_);
    const int bwc = aval ? bw_l : 0;
    const int b = bwc / W_;
    const int w = bwc - b * W_;
    const float* arow = cFeat + (size_t)(b * S_ + w) * DAR_;

    const int erow = nt * 64 + lr;
    const float* brow = Wp + (size_t)(k * DENC_ + erow) * DAR_;

    float acc[4][4];
#pragma unroll
    for (int i = 0; i < 4; ++i)
#pragma unroll
        for (int j = 0; j < 4; ++j) acc[i][j] = 0.0f;

    for (int d0 = 0; d0 < DAR_; d0 += 16) {
        float4 av = aval ? *(const float4*)(arow + d0 + dg * 4)
                         : make_float4(0.f, 0.f, 0.f, 0.f);
        float4 bv = *(const float4*)(brow + d0 + dg * 4);

        __syncthreads();
        As[(dg * 4 + 0) * 64 + lr] = av.x;
        As[(dg * 4 + 1) * 64 + lr] = av.y;
        As[(dg * 4 + 2) * 64 + lr] = av.z;
        As[(dg * 4 + 3) * 64 + lr] = av.w;
        Bs[(dg * 4 + 0) * 64 + lr] = bv.x;
        Bs[(dg * 4 + 1) * 64 + lr] = bv.y;
        Bs[(dg * 4 + 2) * 64 + lr] = bv.z;
        Bs[(dg * 4 + 3) * 64 + lr] = bv.w;
        __syncthreads();

#pragma unroll
        for (int d = 0; d < 16; ++d) {
            float4 aa = *(const float4*)&As[d * 64 + ty * 4];
            float4 bb = *(const float4*)&Bs[d * 64 + tx * 4];
            float ar[4] = {aa.x, aa.y, aa.z, aa.w};
            float br[4] = {bb.x, bb.y, bb.z, bb.w};
#pragma unroll
            for (int i = 0; i < 4; ++i)
#pragma unroll
                for (int j = 0; j < 4; ++j)
                    acc[i][j] = fmaf(ar[i], br[j], acc[i][j]);
        }
    }

    const int e0 = nt * 64 + tx * 4;
#pragma unroll
    for (int i = 0; i < 4; ++i) {
        const int bwo = mt * 64 + ty * 4 + i;
        if (bwo < BW_) {
            float4 v = make_float4(acc[i][0], acc[i][1], acc[i][2], acc[i][3]);
            *(float4*)(locC + ((size_t)k * BW_ + bwo) * DENC_ + e0) = v;
        }
    }
}

// ---------------------------------------------------------------------------
// Stage 2: one block per (b,w). Scores + LSE; writes per-(k,bw) partials to
// workspace (NO global atomics — round-1 showed 22K same-line atomics
// serialized the whole dispatch: 220 us @ 4.7% VALUBusy).
// ---------------------------------------------------------------------------
__global__ __launch_bounds__(256) void stage2_score(
    const float* __restrict__ enc,      // (B, S, DENC)
    const float* __restrict__ locC,     // (K, BW, DENC)
    const int* __restrict__ batchIdx,
    const int* __restrict__ seqIdx,
    float* __restrict__ part)           // (2*K, BW): loss partials then acc partials
{
    __shared__ float lc[K_ * DENC_];        // 12 KB
    __shared__ float buf[2 * K_ * NNEG_];   // 12 KB  (two-step cross-wave combine)
    __shared__ float sc[K_ * 132];          // 6.2 KB (129 logits per k, padded)
    __shared__ float posbuf[K_ * 16];       // 768 B

    const int tid = threadIdx.x;
    const int bw = blockIdx.x;              // 0..927
    const int b = bw / W_;
    const int w = bw - b * W_;

    // ---- load the 12 locC rows for this (b,w) into LDS ----
#pragma unroll
    for (int i = 0; i < 3; ++i) {
        const int q4 = tid + 256 * i;       // 0..767 float4 index
        const int k  = q4 >> 6;
        const int e4 = q4 & 63;
        float4 v = *(const float4*)(locC + ((size_t)k * BW_ + bw) * DENC_ + e4 * 4);
        *(float4*)&lc[k * DENC_ + e4 * 4] = v;
    }
    __syncthreads();

    // ---- positive-score partials (192 threads: 12 k x 16 segments) ----
    if (tid < 192) {
        const int k = tid >> 4, seg = tid & 15;
        const float* prow = enc + (size_t)(b * S_ + w + k + 1) * DENC_ + seg * 16;
        const float* lrow = lc + k * DENC_ + seg * 16;
        float s = 0.f;
#pragma unroll
        for (int g = 0; g < 4; ++g) {
            float4 pv = *(const float4*)(prow + g * 4);
            float4 lv = *(const float4*)(lrow + g * 4);
            s += pv.x * lv.x + pv.y * lv.y + pv.z * lv.z + pv.w * lv.w;
        }
        posbuf[tid] = s;
    }

    // ---- negative-score partials ----
    // thread -> e-slice h (8 slices of 32 e), n-base nb (32), 4 n's per thread
    const int h  = tid >> 5;   // 0..7
    const int nb = tid & 31;   // 0..31

    const float* rowp[4];
#pragma unroll
    for (int j = 0; j < 4; ++j) {
        const int n = nb + 32 * j;
        const int i_idx = (b * NNEG_ + n) * W_ + w;
        const int bi = batchIdx[i_idx];
        int si = seqIdx[i_idx] + w;          // seqIdx in [1,S), w <= 115 -> < 243
        if (si >= S_) si -= S_;
        rowp[j] = enc + (size_t)(bi * S_ + si) * DENC_ + h * 32;
    }

    float acc[K_][4];
#pragma unroll
    for (int k = 0; k < K_; ++k)
#pragma unroll
        for (int j = 0; j < 4; ++j) acc[k][j] = 0.f;

    for (int g = 0; g < 8; ++g) {
        float4 v[4];
#pragma unroll
        for (int j = 0; j < 4; ++j) v[j] = *(const float4*)(rowp[j] + g * 4);
#pragma unroll
        for (int k = 0; k < K_; ++k) {
            float4 l = *(const float4*)&lc[k * DENC_ + h * 32 + g * 4];
#pragma unroll
            for (int j = 0; j < 4; ++j) {
                acc[k][j] = fmaf(l.x, v[j].x,
                            fmaf(l.y, v[j].y,
                            fmaf(l.z, v[j].z,
                            fmaf(l.w, v[j].w, acc[k][j]))));
            }
        }
    }

    // combine the two e-slices that live in the same wave (lane ^ 32)
    const int lane = tid & 63;
    const int wave = tid >> 6;
#pragma unroll
    for (int k = 0; k < K_; ++k)
#pragma unroll
        for (int j = 0; j < 4; ++j)
            acc[k][j] += __shfl_xor(acc[k][j], 32, 64);

    // two-step cross-wave combine using a 2-wave buffer (saves 12 KB LDS vs
    // 4-wave buffer -> 5 blocks/CU instead of 3):
    //   waves 2,3 write; sync; waves 0,1 add in place; sync; everyone sums pairs.
    if (wave >= 2 && lane < 32) {
#pragma unroll
        for (int k = 0; k < K_; ++k)
#pragma unroll
            for (int j = 0; j < 4; ++j)
                buf[(wave - 2) * (K_ * NNEG_) + k * NNEG_ + nb + 32 * j] = acc[k][j];
    }
    __syncthreads();
    if (wave < 2 && lane < 32) {
#pragma unroll
        for (int k = 0; k < K_; ++k)
#pragma unroll
            for (int j = 0; j < 4; ++j)
                buf[wave * (K_ * NNEG_) + k * NNEG_ + nb + 32 * j] += acc[k][j];
    }
    __syncthreads();

    // ---- final reduction into the logit table sc[k][0..128] ----
    const float inv_denc = 1.0f / (float)DENC_;
#pragma unroll
    for (int i = 0; i < 6; ++i) {
        const int p = tid + 256 * i;        // 0..1535
        const int k = p >> 7;
        const int n = p & 127;
        float s = buf[k * NNEG_ + n] + buf[K_ * NNEG_ + k * NNEG_ + n];
        sc[k * 132 + 1 + n] = s * inv_denc;
    }
    if (tid < K_) {
        float s = 0.f;
#pragma unroll
        for (int seg = 0; seg < 16; ++seg) s += posbuf[tid * 16 + seg];
        sc[tid * 132] = s * inv_denc;
    }
    __syncthreads();

    // ---- LSE + argmax per k (wave wv handles k = wv, wv+4, wv+8) ----
    for (int k = wave; k < K_; k += 4) {
        const float sc0 = sc[k * 132];              // logit j=0 (pos)
        const float a  = sc[k * 132 + lane];        // j = lane   (0..63)
        const float b2 = sc[k * 132 + 64 + lane];   // j = 64+lane (64..127)
        const float cc = (lane == 0) ? sc[k * 132 + 128] : -INFINITY;  // j=128
        const float an = (lane == 0) ? -INFINITY : a;  // exclude j=0 from neg-max

        float mn = fmaxf(fmaxf(an, b2), cc);
#pragma unroll
        for (int off = 1; off < 64; off <<= 1)
            mn = fmaxf(mn, __shfl_xor(mn, off, 64));

        const float m = fmaxf(mn, sc0);             // global max for stability
        float s = expf(a - m) + expf(b2 - m) + expf(cc - m);
#pragma unroll
        for (int off = 1; off < 64; off <<= 1)
            s += __shfl_xor(s, off, 64);

        if (lane == 0) {
            const float lse = m + logf(s);
            part[k * BW_ + bw]          = lse - sc0;
            part[(K_ + k) * BW_ + bw]   = (sc0 >= mn) ? 1.0f : 0.0f;
        }
    }
}

// ---------------------------------------------------------------------------
// Stage 3: reduce the (2K, BW) partial table to the 24 outputs. One block per
// output; plain stores, no atomics. Also serves as the d_out initializer.
// ---------------------------------------------------------------------------
__global__ __launch_bounds__(256) void stage3_reduce(
    const float* __restrict__ part,     // (2*K, BW)
    float* __restrict__ out)            // 24 floats
{
    __shared__ float wsum[4];
    const int o = blockIdx.x;           // 0..23
    const int tid = threadIdx.x;

    float s = 0.f;
    for (int i = tid; i < BW_; i += 256) s += part[o * BW_ + i];
#pragma unroll
    for (int off = 1; off < 64; off <<= 1) s += __shfl_xor(s, off, 64);
    if ((tid & 63) == 0) wsum[tid >> 6] = s;
    __syncthreads();
    if (tid == 0)
        out[o] = (wsum[0] + wsum[1] + wsum[2] + wsum[3]) / (float)BW_;
}

// ---------------------------------------------------------------------------
extern "C" void kernel_launch(void* const* d_in, const int* in_sizes, int n_in,
                              void* d_out, int out_size, void* d_ws, size_t ws_size,
                              hipStream_t stream) {
    const float* cFeat    = (const float*)d_in[0];
    const float* enc      = (const float*)d_in[1];
    const float* Wp       = (const float*)d_in[2];
    const int*   batchIdx = (const int*)d_in[3];
    const int*   seqIdx   = (const int*)d_in[4];
    float* out  = (float*)d_out;

    float* locC = (float*)d_ws;                         // (K, BW, DENC) = 11.4 MB
    float* part = locC + (size_t)K_ * BW_ * DENC_;      // (2K, BW) = 89 KB

    hipLaunchKernelGGL(stage1_gemm, dim3(15, 4, 12), dim3(256), 0, stream,
                       cFeat, Wp, locC);
    hipLaunchKernelGGL(stage2_score, dim3(BW_), dim3(256), 0, stream,
                       enc, locC, batchIdx, seqIdx, part);
    hipLaunchKernelGGL(stage3_reduce, dim3(24), dim3(256), 0, stream,
                       part, out);
}

// Round 3
// 95.253 us; speedup vs baseline: 3.1987x; 1.4022x over previous
//
#include <hip/hip_runtime.h>
#include <math.h>

#define B_    8
#define S_    128
#define K_    12
#define DAR_  256
#define DENC_ 256
#define NNEG_ 128
#define W_    116          // S - K
#define BW_   928          // B * W

typedef __attribute__((ext_vector_type(8))) short short8;   // 8 bf16 (4 VGPRs)
typedef __attribute__((ext_vector_type(4))) float floatx4;  // MFMA C/D

static __device__ __forceinline__ unsigned short f2bf(float f) {
    union { float f; unsigned int u; } v; v.f = f;
    return (unsigned short)((v.u + 0x7FFFu + ((v.u >> 16) & 1u)) >> 16);  // RNE
}

// ---------------------------------------------------------------------------
// Cast enc / cFeat / Wpred to bf16 in one pass. 163840 chunks of 8 floats.
// ---------------------------------------------------------------------------
__global__ __launch_bounds__(256) void cast_all(
    const float* __restrict__ enc, const float* __restrict__ cf,
    const float* __restrict__ wp,
    unsigned short* __restrict__ ench, unsigned short* __restrict__ cfh,
    unsigned short* __restrict__ wph)
{
    const int g = blockIdx.x * 256 + threadIdx.x;   // 0..163839
    const float* src; unsigned short* dst; int off;
    if (g < 32768)      { src = enc; dst = ench; off = g * 8; }
    else if (g < 65536) { src = cf;  dst = cfh;  off = (g - 32768) * 8; }
    else                { src = wp;  dst = wph;  off = (g - 65536) * 8; }
    float4 v0 = *(const float4*)(src + off);
    float4 v1 = *(const float4*)(src + off + 4);
    uint4 o;
    o.x = f2bf(v0.x) | ((unsigned)f2bf(v0.y) << 16);
    o.y = f2bf(v0.z) | ((unsigned)f2bf(v0.w) << 16);
    o.z = f2bf(v1.x) | ((unsigned)f2bf(v1.y) << 16);
    o.w = f2bf(v1.z) | ((unsigned)f2bf(v1.w) << 16);
    *(uint4*)(dst + off) = o;
}

// ---------------------------------------------------------------------------
// Stage 1 (MFMA): locC[k][bw][e] = sum_d c[bw][d] * Wp[k][e][d], bf16 out.
// 64x64 tile per block, full K=256 staged in LDS with XOR-16B-chunk swizzle.
// ---------------------------------------------------------------------------
__global__ __launch_bounds__(256) void stage1_mfma(
    const unsigned short* __restrict__ cfh,   // (B,S,256) bf16
    const unsigned short* __restrict__ wph,   // (K,256,256) bf16
    unsigned short* __restrict__ locCh)       // (K,BW,256) bf16
{
    __shared__ unsigned short Ah[64 * 256];   // 32 KB, swizzled
    __shared__ unsigned short Bh[64 * 256];   // 32 KB, swizzled

    const int tid = threadIdx.x;
    const int mt = blockIdx.x;                // 15 bw-tiles (last partial)
    const int nt = blockIdx.y;                // 4 e-tiles
    const int k  = blockIdx.z;                // 12

#pragma unroll
    for (int i = 0; i < 8; ++i) {
        const int flat = i * 256 + tid;       // 0..2047 16B-chunks
        const int row = flat >> 5, ch = flat & 31;
        const int sw = (row * 32 + (ch ^ (row & 7))) * 8;
        const int bw = mt * 64 + row;
        uint4 av = make_uint4(0u, 0u, 0u, 0u);
        if (bw < BW_) {
            const int b = bw / W_, w = bw - b * W_;
            av = *(const uint4*)(cfh + ((size_t)(b * S_ + w) * 256 + ch * 8));
        }
        *(uint4*)&Ah[sw] = av;
        const int e = nt * 64 + row;
        uint4 bv = *(const uint4*)(wph + ((size_t)(k * 256 + e) * 256 + ch * 8));
        *(uint4*)&Bh[sw] = bv;
    }
    __syncthreads();

    const int lane = tid & 63, wv = tid >> 6;
    const int l15 = lane & 15, quad = lane >> 4;

    short8 a[8];
    const int am = wv * 16 + l15;
#pragma unroll
    for (int kt = 0; kt < 8; ++kt) {
        const int ch = kt * 4 + quad;
        a[kt] = *(const short8*)&Ah[(am * 32 + (ch ^ (am & 7))) * 8];
    }

    floatx4 acc[4];
#pragma unroll
    for (int n4 = 0; n4 < 4; ++n4) {
        floatx4 c = {0.f, 0.f, 0.f, 0.f};
        const int bn = n4 * 16 + l15;
#pragma unroll
        for (int kt = 0; kt < 8; ++kt) {
            const int ch = kt * 4 + quad;
            short8 bfrag = *(const short8*)&Bh[(bn * 32 + (ch ^ (bn & 7))) * 8];
            c = __builtin_amdgcn_mfma_f32_16x16x32_bf16(a[kt], bfrag, c, 0, 0, 0);
        }
        acc[n4] = c;
    }

    // D: col(e within subtile)=lane&15, row(bw within subtile)=quad*4+reg
#pragma unroll
    for (int n4 = 0; n4 < 4; ++n4) {
        const int e = nt * 64 + n4 * 16 + l15;
#pragma unroll
        for (int r = 0; r < 4; ++r) {
            const int bwo = mt * 64 + wv * 16 + quad * 4 + r;
            if (bwo < BW_)
                locCh[((size_t)k * BW_ + bwo) * 256 + e] = f2bf(acc[n4][r]);
        }
    }
}

// ---------------------------------------------------------------------------
// Stage 2 (MFMA): block per (b,w). A = locC rows (12, pad 16), B = 140 rows:
// 128 gathered negatives + 12 positives. D (16x144) -> all 129 logits.
// Bl is reused as the logit table after compute (saves LDS -> 2 blocks/CU).
// ---------------------------------------------------------------------------
__global__ __launch_bounds__(256) void stage2_mfma(
    const unsigned short* __restrict__ ench,   // (B,S,256) bf16
    const unsigned short* __restrict__ locCh,  // (K,BW,256) bf16
    const int* __restrict__ batchIdx,
    const int* __restrict__ seqIdx,
    float* __restrict__ part)                  // (2K, BW)
{
    __shared__ unsigned short Al[16 * 256];    // 8 KB; rows 12..15 host idxL
    __shared__ unsigned short Bl[140 * 256];   // 70 KB, swizzled; then sc table
    int*   idxL = (int*)&Al[12 * 256];         // 140 ints in the A pad rows
    float* sc   = (float*)Bl;                  // (12, 132): [0..127]=neg, [128]=pos

    const int tid = threadIdx.x;
    const int bw = blockIdx.x;                 // 0..927
    const int b = bw / W_, w = bw - b * W_;

    // ---- row indices ----
    if (tid < NNEG_) {
        const int ii = (b * NNEG_ + tid) * W_ + w;
        const int bi = batchIdx[ii];
        int si = seqIdx[ii] + w;               // < 243
        if (si >= S_) si -= S_;
        idxL[tid] = bi * S_ + si;
    } else if (tid < 140) {
        idxL[tid] = b * S_ + w + 1 + (tid - 128);   // positives k=0..11
    }

    // ---- A staging: locC rows 0..11 (384 chunks) ----
    {
        const int row = tid >> 5, ch = tid & 31;
        uint4 v = *(const uint4*)(locCh + ((size_t)row * BW_ + bw) * 256 + ch * 8);
        *(uint4*)&Al[(row * 32 + (ch ^ (row & 7))) * 8] = v;
    }
    if (tid < 128) {
        const int f2 = 256 + tid;
        const int row = f2 >> 5, ch = f2 & 31;
        uint4 v = *(const uint4*)(locCh + ((size_t)row * BW_ + bw) * 256 + ch * 8);
        *(uint4*)&Al[(row * 32 + (ch ^ (row & 7))) * 8] = v;
    }
    __syncthreads();

    // ---- B gather: 140 rows x 32 chunks = 4480 (coalesced 512B bursts) ----
#pragma unroll
    for (int i = 0; i < 18; ++i) {
        const int flat = i * 256 + tid;
        if (flat < 4480) {
            const int row = flat >> 5, ch = flat & 31;
            const int ri = idxL[row];
            uint4 v = *(const uint4*)(ench + (size_t)ri * 256 + ch * 8);
            *(uint4*)&Bl[(row * 32 + (ch ^ (row & 7))) * 8] = v;
        }
    }
    __syncthreads();

    const int lane = tid & 63, wv = tid >> 6;
    const int l15 = lane & 15, quad = lane >> 4;

    short8 a[8];
#pragma unroll
    for (int kt = 0; kt < 8; ++kt) {
        const int ch = kt * 4 + quad;
        a[kt] = *(const short8*)&Al[(l15 * 32 + (ch ^ (l15 & 7))) * 8];
    }

    // 9 N-tiles over 4 waves: wave wv does tiles wv, wv+4, wv+8
    floatx4 accT[3];
#pragma unroll
    for (int u = 0; u < 3; ++u) {
        const int t = wv + u * 4;
        floatx4 c = {0.f, 0.f, 0.f, 0.f};
        if (t < 9) {
            const int n = t * 16 + l15;
            const int nn = (n < 140) ? n : 128;    // pad cols read row 128 (unused)
#pragma unroll
            for (int kt = 0; kt < 8; ++kt) {
                const int ch = kt * 4 + quad;
                short8 bfrag = *(const short8*)&Bl[(nn * 32 + (ch ^ (nn & 7))) * 8];
                c = __builtin_amdgcn_mfma_f32_16x16x32_bf16(a[kt], bfrag, c, 0, 0, 0);
            }
        }
        accT[u] = c;
    }
    __syncthreads();   // all Bl reads done -> reuse as sc

    const float inv = 1.0f / 256.0f;
#pragma unroll
    for (int u = 0; u < 3; ++u) {
        const int t = wv + u * 4;
        if (t < 9) {
#pragma unroll
            for (int r = 0; r < 4; ++r) {
                const int m = quad * 4 + r;
                if (m < K_) {
                    const float val = accT[u][r] * inv;
                    if (t < 8)           sc[m * 132 + t * 16 + l15] = val;  // negatives
                    else if (l15 == m)   sc[m * 132 + 128] = val;           // pos diag
                }
            }
        }
    }
    __syncthreads();

    // ---- LSE + acc per k (wave wv: k = wv, wv+4, wv+8) ----
    for (int k = wv; k < K_; k += 4) {
        const float x0  = sc[k * 132 + lane];        // neg 0..63
        const float x1  = sc[k * 132 + 64 + lane];   // neg 64..127
        const float pos = sc[k * 132 + 128];
        float mn = fmaxf(x0, x1);
#pragma unroll
        for (int o = 1; o < 64; o <<= 1) mn = fmaxf(mn, __shfl_xor(mn, o, 64));
        const float m = fmaxf(mn, pos);
        float s = __expf(x0 - m) + __expf(x1 - m);
#pragma unroll
        for (int o = 1; o < 64; o <<= 1) s += __shfl_xor(s, o, 64);
        if (lane == 0) {
            const float lse = m + __logf(s + __expf(pos - m));
            part[k * BW_ + bw]        = lse - pos;
            part[(K_ + k) * BW_ + bw] = (pos >= mn) ? 1.0f : 0.0f;
        }
    }
}

// ---------------------------------------------------------------------------
// Stage 3: reduce (2K, BW) partials to the 24 outputs.
// ---------------------------------------------------------------------------
__global__ __launch_bounds__(256) void stage3_reduce(
    const float* __restrict__ part, float* __restrict__ out)
{
    __shared__ float wsum[4];
    const int o = blockIdx.x, tid = threadIdx.x;
    float s = 0.f;
    for (int i = tid; i < BW_; i += 256) s += part[o * BW_ + i];
#pragma unroll
    for (int off = 1; off < 64; off <<= 1) s += __shfl_xor(s, off, 64);
    if ((tid & 63) == 0) wsum[tid >> 6] = s;
    __syncthreads();
    if (tid == 0)
        out[o] = (wsum[0] + wsum[1] + wsum[2] + wsum[3]) / (float)BW_;
}

// ---------------------------------------------------------------------------
extern "C" void kernel_launch(void* const* d_in, const int* in_sizes, int n_in,
                              void* d_out, int out_size, void* d_ws, size_t ws_size,
                              hipStream_t stream) {
    const float* cFeat    = (const float*)d_in[0];
    const float* enc      = (const float*)d_in[1];
    const float* Wp       = (const float*)d_in[2];
    const int*   batchIdx = (const int*)d_in[3];
    const int*   seqIdx   = (const int*)d_in[4];
    float* out = (float*)d_out;

    unsigned short* ench  = (unsigned short*)d_ws;            // 262144 bf16
    unsigned short* cfh   = ench + 262144;                    // 262144 bf16
    unsigned short* wph   = cfh + 262144;                     // 786432 bf16
    unsigned short* locCh = wph + 786432;                     // K*BW*256 bf16
    float*          part  = (float*)(locCh + (size_t)K_ * BW_ * 256);  // (2K,BW)

    hipLaunchKernelGGL(cast_all, dim3(640), dim3(256), 0, stream,
                       enc, cFeat, Wp, ench, cfh, wph);
    hipLaunchKernelGGL(stage1_mfma, dim3(15, 4, 12), dim3(256), 0, stream,
                       cfh, wph, locCh);
    hipLaunchKernelGGL(stage2_mfma, dim3(BW_), dim3(256), 0, stream,
                       ench, locCh, batchIdx, seqIdx, part);
    hipLaunchKernelGGL(stage3_reduce, dim3(24), dim3(256), 0, stream,
                       part, out);
}

// Round 4
// 92.927 us; speedup vs baseline: 3.2787x; 1.0250x over previous
//
#include <hip/hip_runtime.h>
#include <math.h>

#define B_    8
#define S_    128
#define K_    12
#define DAR_  256
#define DENC_ 256
#define NNEG_ 128
#define W_    116          // S - K
#define BW_   928          // B * W

typedef __attribute__((ext_vector_type(8))) short short8;   // 8 bf16 (4 VGPRs)
typedef __attribute__((ext_vector_type(4))) float floatx4;  // MFMA C/D

static __device__ __forceinline__ unsigned short f2bf(float f) {
    union { float f; unsigned int u; } v; v.f = f;
    return (unsigned short)((v.u + 0x7FFFu + ((v.u >> 16) & 1u)) >> 16);  // RNE
}

// ---------------------------------------------------------------------------
// Cast enc / cFeat / Wpred to bf16 in one pass. 163840 chunks of 8 floats.
// ---------------------------------------------------------------------------
__global__ __launch_bounds__(256) void cast_all(
    const float* __restrict__ enc, const float* __restrict__ cf,
    const float* __restrict__ wp,
    unsigned short* __restrict__ ench, unsigned short* __restrict__ cfh,
    unsigned short* __restrict__ wph)
{
    const int g = blockIdx.x * 256 + threadIdx.x;   // 0..163839
    const float* src; unsigned short* dst; int off;
    if (g < 32768)      { src = enc; dst = ench; off = g * 8; }
    else if (g < 65536) { src = cf;  dst = cfh;  off = (g - 32768) * 8; }
    else                { src = wp;  dst = wph;  off = (g - 65536) * 8; }
    float4 v0 = *(const float4*)(src + off);
    float4 v1 = *(const float4*)(src + off + 4);
    uint4 o;
    o.x = f2bf(v0.x) | ((unsigned)f2bf(v0.y) << 16);
    o.y = f2bf(v0.z) | ((unsigned)f2bf(v0.w) << 16);
    o.z = f2bf(v1.x) | ((unsigned)f2bf(v1.y) << 16);
    o.w = f2bf(v1.z) | ((unsigned)f2bf(v1.w) << 16);
    *(uint4*)(dst + off) = o;
}

// ---------------------------------------------------------------------------
// Stage 1 (MFMA): locC[k][bw][e] = sum_d c[bw][d] * Wp[k][e][d], bf16 out.
// B (Wpred 64-row tile) staged in LDS (reused by all 4 waves); A fragments
// loaded DIRECTLY from global (each is 8 contiguous bf16 = one uint4).
// ---------------------------------------------------------------------------
__global__ __launch_bounds__(256) void stage1_mfma(
    const unsigned short* __restrict__ cfh,   // (B,S,256) bf16
    const unsigned short* __restrict__ wph,   // (K,256,256) bf16
    unsigned short* __restrict__ locCh)       // (K,BW,256) bf16
{
    __shared__ unsigned short Bh[64 * 256];   // 32 KB, swizzled

    const int tid = threadIdx.x;
    const int mt = blockIdx.x;                // 15 bw-tiles (last partial)
    const int nt = blockIdx.y;                // 4 e-tiles
    const int k  = blockIdx.z;                // 12

    const int lane = tid & 63, wv = tid >> 6;
    const int l15 = lane & 15, quad = lane >> 4;

    // ---- A fragments direct from global (issue before B staging) ----
    const int am = mt * 64 + wv * 16 + l15;   // bw row
    const bool avalid = (am < BW_);
    short8 a[8];
    if (avalid) {
        const int b = am / W_, w = am - b * W_;
        const unsigned short* arow = cfh + (size_t)(b * S_ + w) * 256;
#pragma unroll
        for (int kt = 0; kt < 8; ++kt)
            a[kt] = *(const short8*)(arow + kt * 32 + quad * 8);
    } else {
#pragma unroll
        for (int kt = 0; kt < 8; ++kt) a[kt] = short8{0,0,0,0,0,0,0,0};
    }

    // ---- B staging: 64 rows x 32 chunks = 2048, 8 per thread ----
#pragma unroll
    for (int i = 0; i < 8; ++i) {
        const int flat = i * 256 + tid;
        const int row = flat >> 5, ch = flat & 31;
        const int e = nt * 64 + row;
        uint4 bv = *(const uint4*)(wph + ((size_t)(k * 256 + e) * 256 + ch * 8));
        *(uint4*)&Bh[(row * 32 + (ch ^ (row & 7))) * 8] = bv;
    }
    __syncthreads();

    floatx4 acc[4];
#pragma unroll
    for (int n4 = 0; n4 < 4; ++n4) {
        floatx4 c = {0.f, 0.f, 0.f, 0.f};
        const int bn = n4 * 16 + l15;
#pragma unroll
        for (int kt = 0; kt < 8; ++kt) {
            const int ch = kt * 4 + quad;
            short8 bfrag = *(const short8*)&Bh[(bn * 32 + (ch ^ (bn & 7))) * 8];
            c = __builtin_amdgcn_mfma_f32_16x16x32_bf16(a[kt], bfrag, c, 0, 0, 0);
        }
        acc[n4] = c;
    }

    // D: col(e within subtile)=lane&15, row(bw within subtile)=quad*4+reg
#pragma unroll
    for (int n4 = 0; n4 < 4; ++n4) {
        const int e = nt * 64 + n4 * 16 + l15;
#pragma unroll
        for (int r = 0; r < 4; ++r) {
            const int bwo = mt * 64 + wv * 16 + quad * 4 + r;
            if (bwo < BW_)
                locCh[((size_t)k * BW_ + bwo) * 256 + e] = f2bf(acc[r < 0 ? 0 : n4][r]);
        }
    }
}

// ---------------------------------------------------------------------------
// Stage 2 (MFMA): block per (b,w). NO A/B LDS staging — fragments loaded
// directly from global (A = locC rows, B = gathered enc rows). LDS is only
// the 140 row indices + the 12x129 logit table (~7 KB -> high occupancy).
// ---------------------------------------------------------------------------
__global__ __launch_bounds__(256) void stage2_mfma(
    const unsigned short* __restrict__ ench,   // (B,S,256) bf16
    const unsigned short* __restrict__ locCh,  // (K,BW,256) bf16
    const int* __restrict__ batchIdx,
    const int* __restrict__ seqIdx,
    float* __restrict__ part)                  // (2K, BW)
{
    __shared__ int   idxL[144];
    __shared__ float sc[K_ * 132];   // [0..127]=neg, [128]=pos

    const int tid = threadIdx.x;
    const int bw = blockIdx.x;                 // 0..927
    const int b = bw / W_, w = bw - b * W_;

    const int lane = tid & 63, wv = tid >> 6;
    const int l15 = lane & 15, quad = lane >> 4;

    // ---- A fragments direct from global (independent of idxL) ----
    const int m = (l15 < K_) ? l15 : (K_ - 1);   // rows 12..15 dup row 11 (ignored)
    const unsigned short* arow = locCh + ((size_t)m * BW_ + bw) * 256;
    short8 a[8];
#pragma unroll
    for (int kt = 0; kt < 8; ++kt)
        a[kt] = *(const short8*)(arow + kt * 32 + quad * 8);

    // ---- row indices ----
    if (tid < NNEG_) {
        const int ii = (b * NNEG_ + tid) * W_ + w;
        const int bi = batchIdx[ii];
        int si = seqIdx[ii] + w;               // seqIdx in [1,S), w <= 115 -> < 243
        if (si >= S_) si -= S_;
        idxL[tid] = bi * S_ + si;
    } else if (tid < 140) {
        idxL[tid] = b * S_ + w + 1 + (tid - 128);   // positives k=0..11
    }
    __syncthreads();

    // ---- 9 N-tiles over 4 waves (wv, wv+4, wv+8); B frags direct gather ----
    floatx4 accT[3];
#pragma unroll
    for (int u = 0; u < 3; ++u) {
        const int t = wv + u * 4;
        floatx4 c = {0.f, 0.f, 0.f, 0.f};
        if (t < 9) {
            const int n = t * 16 + l15;
            const int nn = (n < 140) ? n : 128;    // pad cols dup row 128 (unused)
            const unsigned short* brow = ench + (size_t)idxL[nn] * 256;
#pragma unroll
            for (int kt = 0; kt < 8; ++kt) {
                short8 bfrag = *(const short8*)(brow + kt * 32 + quad * 8);
                c = __builtin_amdgcn_mfma_f32_16x16x32_bf16(a[kt], bfrag, c, 0, 0, 0);
            }
        }
        accT[u] = c;
    }

    const float inv = 1.0f / 256.0f;
#pragma unroll
    for (int u = 0; u < 3; ++u) {
        const int t = wv + u * 4;
        if (t < 9) {
#pragma unroll
            for (int r = 0; r < 4; ++r) {
                const int mm = quad * 4 + r;       // accumulator row = k index
                if (mm < K_) {
                    const float val = accT[u][r] * inv;
                    if (t < 8)           sc[mm * 132 + t * 16 + l15] = val;  // neg
                    else if (l15 == mm)  sc[mm * 132 + 128] = val;           // pos
                }
            }
        }
    }
    __syncthreads();

    // ---- LSE + acc per k (wave wv: k = wv, wv+4, wv+8) ----
    for (int k = wv; k < K_; k += 4) {
        const float x0  = sc[k * 132 + lane];        // neg 0..63
        const float x1  = sc[k * 132 + 64 + lane];   // neg 64..127
        const float pos = sc[k * 132 + 128];
        float mn = fmaxf(x0, x1);
#pragma unroll
        for (int o = 1; o < 64; o <<= 1) mn = fmaxf(mn, __shfl_xor(mn, o, 64));
        const float m2 = fmaxf(mn, pos);
        float s = __expf(x0 - m2) + __expf(x1 - m2);
#pragma unroll
        for (int o = 1; o < 64; o <<= 1) s += __shfl_xor(s, o, 64);
        if (lane == 0) {
            const float lse = m2 + __logf(s + __expf(pos - m2));
            part[k * BW_ + bw]        = lse - pos;
            part[(K_ + k) * BW_ + bw] = (pos >= mn) ? 1.0f : 0.0f;
        }
    }
}

// ---------------------------------------------------------------------------
// Stage 3: reduce (2K, BW) partials to the 24 outputs.
// ---------------------------------------------------------------------------
__global__ __launch_bounds__(256) void stage3_reduce(
    const float* __restrict__ part, float* __restrict__ out)
{
    __shared__ float wsum[4];
    const int o = blockIdx.x, tid = threadIdx.x;
    float s = 0.f;
    for (int i = tid; i < BW_; i += 256) s += part[o * BW_ + i];
#pragma unroll
    for (int off = 1; off < 64; off <<= 1) s += __shfl_xor(s, off, 64);
    if ((tid & 63) == 0) wsum[tid >> 6] = s;
    __syncthreads();
    if (tid == 0)
        out[o] = (wsum[0] + wsum[1] + wsum[2] + wsum[3]) / (float)BW_;
}

// ---------------------------------------------------------------------------
extern "C" void kernel_launch(void* const* d_in, const int* in_sizes, int n_in,
                              void* d_out, int out_size, void* d_ws, size_t ws_size,
                              hipStream_t stream) {
    const float* cFeat    = (const float*)d_in[0];
    const float* enc      = (const float*)d_in[1];
    const float* Wp       = (const float*)d_in[2];
    const int*   batchIdx = (const int*)d_in[3];
    const int*   seqIdx   = (const int*)d_in[4];
    float* out = (float*)d_out;

    unsigned short* ench  = (unsigned short*)d_ws;            // 262144 bf16
    unsigned short* cfh   = ench + 262144;                    // 262144 bf16
    unsigned short* wph   = cfh + 262144;                     // 786432 bf16
    unsigned short* locCh = wph + 786432;                     // K*BW*256 bf16
    float*          part  = (float*)(locCh + (size_t)K_ * BW_ * 256);  // (2K,BW)

    hipLaunchKernelGGL(cast_all, dim3(640), dim3(256), 0, stream,
                       enc, cFeat, Wp, ench, cfh, wph);
    hipLaunchKernelGGL(stage1_mfma, dim3(15, 4, 12), dim3(256), 0, stream,
                       cfh, wph, locCh);
    hipLaunchKernelGGL(stage2_mfma, dim3(BW_), dim3(256), 0, stream,
                       ench, locCh, batchIdx, seqIdx, part);
    hipLaunchKernelGGL(stage3_reduce, dim3(24), dim3(256), 0, stream,
                       part, out);
}